// Round 6
// baseline (645.672 us; speedup 1.0000x reference)
//
#include <hip/hip_runtime.h>
#include <stdint.h>

// Problem constants (fixed instance from setup_inputs)
#define B_   2
#define T_   64
#define S_   1024
#define C_   512
#define H_   8
#define N_   (T_ * S_)      // 65536
#define M_   (B_ * N_)      // 131072
#define WIN_ 5

typedef unsigned short u16;
typedef __bf16 bf16;
typedef __bf16 bf16x8 __attribute__((ext_vector_type(8)));
typedef float  f32x4  __attribute__((ext_vector_type(4)));
typedef u16    u16x8  __attribute__((ext_vector_type(8)));

static __device__ __forceinline__ u16 f2bf(float f) {
    return __builtin_bit_cast(u16, (bf16)f);   // RNE
}
static __device__ __forceinline__ float bf2f(u16 u) {
    return __builtin_bit_cast(float, (uint32_t)u << 16);
}
// async global->LDS, 16B per lane; LDS dest is wave-uniform base + lane*16
static __device__ __forceinline__ void gload16(const void* g, void* l) {
    __builtin_amdgcn_global_load_lds(
        (const __attribute__((address_space(1))) void*)g,
        (__attribute__((address_space(3))) void*)l, 16, 0, 0);
}

// Pre-swizzle layout (every bf16 [row][512] operand):
// logical (row r, chunk c in [0,16) of 32 elems, granule g in [0,4), elem j)
// stored at r*512 + (c ^ ((r>>3)&1))*32 + ((g ^ ((r>>1)&3))<<3) + j.
// The GEMM stage undoes the chunk-XOR via per-lane source addressing; the
// granule-XOR is kept in LDS and undone at frag-read (<=2-way conflicts=free).

// ---------------------------------------------------------------------------
// Weight prep: W [512][NCOL] fp32 -> WT [NCOL][512] bf16, pre-swizzled.
// ---------------------------------------------------------------------------
__global__ __launch_bounds__(256) void prep_w(const float* __restrict__ W,
                                              u16* __restrict__ WT, int NCOL) {
    int id = blockIdx.x * 256 + threadIdx.x;
    int n  = id % NCOL;
    int gi = id / NCOL;
    int chunk = gi >> 2;
    int g     = gi & 3;
    int k0 = chunk * 32 + g * 8;
    int cs = chunk ^ ((n >> 3) & 1);
    int gs = g ^ ((n >> 1) & 3);
    u16x8 w;
    #pragma unroll
    for (int j = 0; j < 8; ++j) w[j] = f2bf(W[(size_t)(k0 + j) * NCOL + n]);
    *(u16x8*)&WT[(size_t)n * 512 + cs * 32 + gs * 8] = w;
}

// ---------------------------------------------------------------------------
// x prep: x [M][512] fp32 -> xb [M][512] bf16, pre-swizzled.
// ---------------------------------------------------------------------------
__global__ __launch_bounds__(256) void prep_x(const float* __restrict__ x,
                                              u16* __restrict__ xb) {
    const size_t total = (size_t)M_ * 64;   // 16B granules
    for (size_t id = (size_t)blockIdx.x * 256 + threadIdx.x; id < total;
         id += (size_t)gridDim.x * 256) {
        size_t r  = id >> 6;
        int   gi  = (int)(id & 63);
        int chunk = gi >> 2;
        int g     = gi & 3;
        int cb    = ((int)r >> 3) & 1;
        int key   = ((int)r >> 1) & 3;
        const float* src = x + r * 512 + chunk * 32 + g * 8;
        u16x8 w;
        #pragma unroll
        for (int j = 0; j < 8; ++j) w[j] = f2bf(src[j]);
        *(u16x8*)&xb[r * 512 + (chunk ^ cb) * 32 + ((g ^ key) << 3)] = w;
    }
}

#define LDF(off) __builtin_bit_cast(bf16x8, *(const u16x8*)&lds[(off)])
#define MFMA16(d, a, b) d = __builtin_amdgcn_mfma_f32_16x16x32_bf16(a, b, d, 0, 0, 0)

// ---------------------------------------------------------------------------
// 256x256 GEMM, BK=32, 4 LDS buffers, 2 balanced phases/K-tile, frag-prefetch
// one phase ahead with counted (compiler-derived) lgkm waits.
//   ph0: read B(t) 4 + A(t+1) mf0-3 4; stage A(t+3); bar; MFMA Q-left; bar.
//   ph1: read A(t+1) mf4-7 4;          stage B(t+3); bar; MFMA Q-right;
//        vmcnt(4) [t+2 landed, t+3 in flight]; bar.
// WAR: stage(t+3) overwrites buf((t-1)&3); all reads of it completed before
// the t-1 ph1-end barrier (in-order DS + auto-lgkm before t-1's MFMAs).
// Landed-guarantee: reads of buf(t+1) at tile t follow tile t-1's vmcnt(4)
// (<=4 outstanding = t+2's stages) + barrier.
// ---------------------------------------------------------------------------
template<int NCOL, bool OUT_BF16>
__global__ __launch_bounds__(512, 2) void gemm8_k(const u16* __restrict__ Ap,
                                                  const u16* __restrict__ Bp,
                                                  void* __restrict__ Dp, int gx) {
    __shared__ u16 lds[65536];   // 4 bufs x 16384 u16 (A 8192 | B 8192)

    const int tid  = threadIdx.x;
    const int lane = tid & 63;
    const int wid  = tid >> 6;    // 0..7
    const int wm   = wid >> 2;    // 0..1
    const int wn   = wid & 3;     // 0..3
    const int fr   = lane & 15;
    const int g0   = lane >> 4;

    // XCD-aware bijective swizzle (grid % 8 == 0)
    const int nwg = gridDim.x;
    const int q8  = nwg >> 3;
    const int bid = blockIdx.x;
    const int wg  = (bid & 7) * q8 + (bid >> 3);
    const int bx  = wg % gx;
    const int by  = wg / gx;
    const long row0 = (long)by * 256;
    const int  col0 = bx * 256;

    // frag LDS offsets (u16, within A/B region of a buffer): row*32 + granule swz
    int aoffs[8], boffs[4];
    #pragma unroll
    for (int mf = 0; mf < 8; ++mf) {
        int lr = wm * 128 + mf * 16 + fr;
        aoffs[mf] = lr * 32 + (((g0 ^ (lr >> 1)) & 3) << 3);
    }
    #pragma unroll
    for (int nf = 0; nf < 4; ++nf) {
        int lc = wn * 64 + nf * 16 + fr;
        boffs[nf] = lc * 32 + (((g0 ^ (lc >> 1)) & 3) << 3);
    }

    // staging: per call 2 gload16/thread; rows i*128 + wid*16 + (lane>>2),
    // source chunk = t ^ ((row>>3)&1) (undo pre-swizzle chunk-XOR), granule
    // copied in stored order (granule swizzle stays in LDS).
    auto stageA = [&](int tt) {
        const int base = (tt & 3) * 16384;
        #pragma unroll
        for (int i = 0; i < 2; ++i) {
            int r = i * 128 + wid * 16 + (lane >> 2);
            long gr = row0 + r;
            const u16* g = Ap + gr * 512 + ((tt ^ ((r >> 3) & 1)) << 5) + ((lane & 3) << 3);
            gload16(g, (void*)&lds[base + (i * 128 + wid * 16) * 32]);
        }
    };
    auto stageB = [&](int tt) {
        const int base = (tt & 3) * 16384 + 8192;
        #pragma unroll
        for (int i = 0; i < 2; ++i) {
            int r = i * 128 + wid * 16 + (lane >> 2);
            size_t gc = (size_t)(col0 + r);
            const u16* g = Bp + gc * 512 + ((tt ^ ((r >> 3) & 1)) << 5) + ((lane & 3) << 3);
            gload16(g, (void*)&lds[base + (i * 128 + wid * 16) * 32]);
        }
    };

    f32x4 acc[8][4] = {};

    // ---- prologue: stage tiles 0,1,2; confirm 0,1 landed (t2 in flight) ----
    stageA(0); stageB(0); stageA(1); stageB(1); stageA(2); stageB(2);
    asm volatile("s_waitcnt vmcnt(4)" ::: "memory");
    __builtin_amdgcn_sched_barrier(0);
    __builtin_amdgcn_s_barrier();

    bf16x8 a[8];
    #pragma unroll
    for (int mf = 0; mf < 8; ++mf) a[mf] = LDF(aoffs[mf]);   // A(0), buf0

    #pragma unroll
    for (int t = 0; t < 16; ++t) {
        const int base  = (t & 3) * 16384;
        const int nbase = ((t + 1) & 3) * 16384;
        bf16x8 b[4], an[8];
        // ================= phase 0 =================
        #pragma unroll
        for (int nf = 0; nf < 4; ++nf) b[nf] = LDF(base + 8192 + boffs[nf]);
        if (t < 15) {
            #pragma unroll
            for (int mf = 0; mf < 4; ++mf) an[mf] = LDF(nbase + aoffs[mf]);
        }
        if (t <= 12) stageA(t + 3);
        __builtin_amdgcn_s_barrier();
        __builtin_amdgcn_sched_barrier(0);
        __builtin_amdgcn_s_setprio(1);
        #pragma unroll
        for (int mf = 0; mf < 8; ++mf) {   // Q-left: auto-lgkm waits b[1] only
            MFMA16(acc[mf][0], a[mf], b[0]);
            MFMA16(acc[mf][1], a[mf], b[1]);
        }
        __builtin_amdgcn_s_setprio(0);
        __builtin_amdgcn_sched_barrier(0);
        __builtin_amdgcn_s_barrier();
        // ================= phase 1 =================
        if (t < 15) {
            #pragma unroll
            for (int mf = 4; mf < 8; ++mf) an[mf] = LDF(nbase + aoffs[mf]);
        }
        if (t <= 12) stageB(t + 3);
        __builtin_amdgcn_s_barrier();
        __builtin_amdgcn_sched_barrier(0);
        __builtin_amdgcn_s_setprio(1);
        #pragma unroll
        for (int mf = 0; mf < 8; ++mf) {   // Q-right: auto-lgkm waits b[3]
            MFMA16(acc[mf][2], a[mf], b[2]);
            MFMA16(acc[mf][3], a[mf], b[3]);
        }
        __builtin_amdgcn_s_setprio(0);
        __builtin_amdgcn_sched_barrier(0);
        if (t <= 12) {
            asm volatile("s_waitcnt vmcnt(4)" ::: "memory");  // t+2 landed
        } else if (t == 13) {
            asm volatile("s_waitcnt vmcnt(0)" ::: "memory");  // t+3=16 none; drain 15
        }
        __builtin_amdgcn_sched_barrier(0);
        __builtin_amdgcn_s_barrier();
        // rotate prefetched A frags (renamed away by full unroll)
        if (t < 15) {
            #pragma unroll
            for (int mf = 0; mf < 8; ++mf) a[mf] = an[mf];
        }
    }

    // ---- epilogue: C row = (lane>>4)*4 + r, col = lane&15 ----
    #pragma unroll
    for (int mf = 0; mf < 8; ++mf) {
        #pragma unroll
        for (int nf = 0; nf < 4; ++nf) {
            #pragma unroll
            for (int r = 0; r < 4; ++r) {
                long grow = row0 + wm * 128 + mf * 16 + (lane >> 4) * 4 + r;
                int  gcol = col0 + wn * 64 + nf * 16 + fr;
                float v = acc[mf][nf][r];
                if constexpr (OUT_BF16) ((u16*)Dp)[grow * NCOL + gcol] = f2bf(v);
                else                    ((float*)Dp)[grow * NCOL + gcol] = v;
            }
        }
    }
}

// ---------------------------------------------------------------------------
// Banded temporal attention. One wave per (b, h, s). qkv layout (linear bf16):
// qkv[((b*T + t)*S + s)*1536 + which*512 + h*64 + d].
// Output rows stored PRE-SWIZZLED (chunk+granule XOR) for gemm3's staging.
// ---------------------------------------------------------------------------
__global__ __launch_bounds__(64) void attn_k(const u16* __restrict__ qkv,
                                             u16* __restrict__ attn) {
    __shared__ u16 Kl[64][72];
    __shared__ u16 Vl[64][72];

    const int tid = threadIdx.x;
    const int bid = blockIdx.x;
    const int s = bid & (S_ - 1);
    const int h = (bid >> 10) & (H_ - 1);
    const int b = bid >> 13;

    const size_t base = ((size_t)b * T_ * S_ + s) * 1536 + h * 64;

    {
        const int rr = tid >> 3;
        const int ch = tid & 7;
        #pragma unroll
        for (int it = 0; it < 8; ++it) {
            int tt = it * 8 + rr;
            size_t off = base + (size_t)tt * (S_ * 1536) + ch * 8;
            *(u16x8*)&Kl[tt][ch * 8] = *(const u16x8*)(qkv + off + 512);
            *(u16x8*)&Vl[tt][ch * 8] = *(const u16x8*)(qkv + off + 1024);
        }
    }
    float qf[64];
    const int t = tid;
    {
        size_t qoff = base + (size_t)t * (S_ * 1536);
        #pragma unroll
        for (int c = 0; c < 8; ++c) {
            u16x8 v = *(const u16x8*)(qkv + qoff + c * 8);
            #pragma unroll
            for (int j = 0; j < 8; ++j) qf[c * 8 + j] = bf2f(v[j]);
        }
    }
    __syncthreads();

    float p[11];
    float m = -1e30f;
    #pragma unroll
    for (int i = 0; i < 11; ++i) {
        int u = t - WIN_ + i;
        if (u >= 0 && u < 64) {
            float dot = 0.f;
            #pragma unroll
            for (int c = 0; c < 8; ++c) {
                u16x8 kv = *(const u16x8*)&Kl[u][c * 8];
                #pragma unroll
                for (int j = 0; j < 8; ++j) dot += qf[c * 8 + j] * bf2f(kv[j]);
            }
            p[i] = dot * 0.125f;
            m = fmaxf(m, p[i]);
        } else {
            p[i] = -1e30f;
        }
    }
    float sum = 0.f;
    #pragma unroll
    for (int i = 0; i < 11; ++i) {
        int u = t - WIN_ + i;
        float e = (u >= 0 && u < 64) ? __expf(p[i] - m) : 0.f;
        p[i] = e;
        sum += e;
    }
    const float inv = 1.f / sum;

    float o[64];
    #pragma unroll
    for (int d = 0; d < 64; ++d) o[d] = 0.f;
    #pragma unroll
    for (int i = 0; i < 11; ++i) {
        int u = t - WIN_ + i;
        if (u >= 0 && u < 64) {
            float pv = p[i] * inv;
            #pragma unroll
            for (int c = 0; c < 8; ++c) {
                u16x8 vv = *(const u16x8*)&Vl[u][c * 8];
                #pragma unroll
                for (int j = 0; j < 8; ++j) o[c * 8 + j] += pv * bf2f(vv[j]);
            }
        }
    }
    // pre-swizzled store: logical chunk 2h+(c>>2), granule c&3, row key from s
    size_t rowbase = (((size_t)b * T_ + t) * S_ + s) * (size_t)C_;
    const int cb  = (s >> 3) & 1;
    const int key = (s >> 1) & 3;
    #pragma unroll
    for (int c = 0; c < 8; ++c) {
        u16x8 w;
        #pragma unroll
        for (int j = 0; j < 8; ++j) w[j] = f2bf(o[c * 8 + j]);
        int off = (((2 * h + (c >> 2)) ^ cb) << 5) + (((c & 3) ^ key) << 3);
        *(u16x8*)&attn[rowbase + off] = w;
    }
}

// ---------------------------------------------------------------------------
extern "C" void kernel_launch(void* const* d_in, const int* in_sizes, int n_in,
                              void* d_out, int out_size, void* d_ws, size_t ws_size,
                              hipStream_t stream) {
    const float* x    = (const float*)d_in[0];   // (B, N, C) fp32
    const float* Wqkv = (const float*)d_in[1];   // (512, 1536) fp32
    const float* Wout = (const float*)d_in[2];   // (512, 512) fp32
    float* out = (float*)d_out;

    const size_t xc_elems  = (size_t)M_ * C_;      // 67.1M (x_bf16 / attn alias)
    const size_t qkv_elems = (size_t)M_ * 1536;    // 201.3M
    if (ws_size < (xc_elems + qkv_elems) * sizeof(u16)) return;  // 537 MiB

    u16* xb       = (u16*)d_ws;              // [0, 134MB): x_bf16, dead after gemm1
    u16* qkv      = xb + xc_elems;           // [134MB, 537MB)
    u16* attn_buf = xb;                      // alias: written after xb is dead
    u16* WqkvT    = (u16*)d_out;             // scratch in d_out (dead until gemm3)
    u16* WoutT    = qkv;                     // alias: written after qkv is dead

    // 1) weight + activation prep (bf16, pre-swizzled)
    prep_w<<<(1536 * 64) / 256, 256, 0, stream>>>(Wqkv, WqkvT, 1536);
    prep_x<<<8192, 256, 0, stream>>>(x, xb);

    // 2) qkv = x @ W_qkv  (256^2 BK=32 4-buf pipelined, bf16 out)
    gemm8_k<1536, true><<<3072, 512, 0, stream>>>(xb, WqkvT, (void*)qkv, 6);

    // 3) banded temporal attention (reads qkv, writes attn_buf pre-swizzled)
    attn_k<<<B_ * H_ * S_, 64, 0, stream>>>(qkv, attn_buf);

    // 4) WoutT into the now-dead qkv region
    prep_w<<<(512 * 64) / 256, 256, 0, stream>>>(Wout, WoutT, 512);

    // 5) out = attn @ W_out  (256^2 BK=32 4-buf pipelined, fp32 out)
    gemm8_k<512, false><<<1024, 512, 0, stream>>>(attn_buf, WoutT, (void*)out, 2);
}

// Round 7
// 611.616 us; speedup vs baseline: 1.0557x; 1.0557x over previous
//
#include <hip/hip_runtime.h>
#include <stdint.h>

// Problem constants (fixed instance from setup_inputs)
#define B_   2
#define T_   64
#define S_   1024
#define C_   512
#define H_   8
#define N_   (T_ * S_)      // 65536
#define M_   (B_ * N_)      // 131072
#define WIN_ 5

typedef unsigned short u16;
typedef __bf16 bf16;
typedef __bf16 bf16x8 __attribute__((ext_vector_type(8)));
typedef float  f32x4  __attribute__((ext_vector_type(4)));
typedef u16    u16x8  __attribute__((ext_vector_type(8)));

static __device__ __forceinline__ u16 f2bf(float f) {
    return __builtin_bit_cast(u16, (bf16)f);   // RNE
}
static __device__ __forceinline__ float bf2f(u16 u) {
    return __builtin_bit_cast(float, (uint32_t)u << 16);
}
// async global->LDS, 16B per lane; LDS dest is wave-uniform base + lane*16
static __device__ __forceinline__ void gload16(const void* g, void* l) {
    __builtin_amdgcn_global_load_lds(
        (const __attribute__((address_space(1))) void*)g,
        (__attribute__((address_space(3))) void*)l, 16, 0, 0);
}
// row permutation: logical (b,t,s) flat row -> physical (b,s,t) flat row
static __device__ __forceinline__ long permute_row(long grow) {
    int b = (int)(grow >> 16);
    int t = (int)(grow >> 10) & 63;
    int s = (int)grow & 1023;
    return ((long)((b << 10) | s)) * 64 + t;
}

// Pre-swizzle layout (every bf16 [row][512] operand, row = PHYSICAL row):
// logical (chunk c in [0,16) of 32 elems, granule g in [0,4), elem j) stored
// at r*512 + (c ^ ((r>>3)&1))*32 + ((g ^ ((r>>1)&3))<<3) + j, keys from the
// row index mod 256 (= the GEMM tile-local LDS row). Chunk-XOR flips bit0 of
// the chunk only (stays within the same BK=64 window); granule-XOR spreads
// the 16B slots so frag ds_read_b128 is <=2-way (free; 0 conflicts measured).

// ---------------------------------------------------------------------------
// Weight prep: W [512][NCOL] fp32 -> WT [NCOL][512] bf16, pre-swizzled.
// Keys from n (col) since B tiles are col-major staged.
// ---------------------------------------------------------------------------
__global__ __launch_bounds__(256) void prep_w(const float* __restrict__ W,
                                              u16* __restrict__ WT, int NCOL) {
    int id = blockIdx.x * 256 + threadIdx.x;
    int n  = id % NCOL;
    int gi = id / NCOL;
    int chunk = gi >> 2;
    int g     = gi & 3;
    int k0 = chunk * 32 + g * 8;
    int cs = chunk ^ ((n >> 3) & 1);
    int gs = g ^ ((n >> 1) & 3);
    u16x8 w;
    #pragma unroll
    for (int j = 0; j < 8; ++j) w[j] = f2bf(W[(size_t)(k0 + j) * NCOL + n]);
    *(u16x8*)&WT[(size_t)n * 512 + cs * 32 + gs * 8] = w;
}

// ---------------------------------------------------------------------------
// x prep: x [M][512] fp32 (rows (b,t,s)) -> xb bf16 rows PERMUTED to (b,s,t),
// pre-swizzled with keys from the permuted row index.
// ---------------------------------------------------------------------------
__global__ __launch_bounds__(256) void prep_x(const float* __restrict__ x,
                                              u16* __restrict__ xb) {
    const size_t total = (size_t)M_ * 64;   // 16B granules
    for (size_t id = (size_t)blockIdx.x * 256 + threadIdx.x; id < total;
         id += (size_t)gridDim.x * 256) {
        long r_in = (long)(id >> 6);
        int  gi   = (int)(id & 63);
        int chunk = gi >> 2;
        int g     = gi & 3;
        long rid  = permute_row(r_in);
        int cb  = (int)(rid >> 3) & 1;
        int key = (int)(rid >> 1) & 3;
        const float* src = x + r_in * 512 + chunk * 32 + g * 8;
        f32x4 v0 = *(const f32x4*)(src);
        f32x4 v1 = *(const f32x4*)(src + 4);
        u16x8 w;
        #pragma unroll
        for (int j = 0; j < 4; ++j) { w[j] = f2bf(v0[j]); w[4 + j] = f2bf(v1[j]); }
        *(u16x8*)&xb[(size_t)rid * 512 + (chunk ^ cb) * 32 + ((g ^ key) << 3)] = w;
    }
}

#define LDF(off) __builtin_bit_cast(bf16x8, *(const u16x8*)&lds[(off)])
#define MFMA16(d, a, b) d = __builtin_amdgcn_mfma_f32_16x16x32_bf16(a, b, d, 0, 0, 0)

// ---------------------------------------------------------------------------
// 256x256 8-phase pipelined GEMM (round-5 structure, best measured: 860 TF).
// A rows: physical = A_PERM ? permute_row(logical) : logical (pre-swizzled
// bf16 [.][512]); B(transposed) [NCOL][512] pre-swizzled bf16.
// 512 thr = 8 waves (2 wm x 4 wn), BK=64, 2 K-tile dbuf (128 KiB LDS).
// Per K-tile t, 4 phases {ds_read subset | stage half-tile | barrier |
// lgkmcnt(0) | 16 MFMA (setprio) | barrier}; vmcnt(4) once per K-tile only.
// ---------------------------------------------------------------------------
template<int NCOL, bool OUT_BF16, bool A_PERM>
__global__ __launch_bounds__(512, 2) void gemm8_k(const u16* __restrict__ Ap,
                                                  const u16* __restrict__ Bp,
                                                  void* __restrict__ Dp, int gx) {
    __shared__ u16 lds[65536];   // dbuf0{A,B} | dbuf1{A,B}, 16384 u16 each

    const int tid  = threadIdx.x;
    const int lane = tid & 63;
    const int wid  = tid >> 6;    // 0..7
    const int wm   = wid >> 2;    // 0..1
    const int wn   = wid & 3;     // 0..3
    const int fr   = lane & 15;
    const int g0   = lane >> 4;

    // XCD-aware bijective swizzle (grid % 8 == 0)
    const int nwg = gridDim.x;
    const int q8  = nwg >> 3;
    const int bid = blockIdx.x;
    const int wg  = (bid & 7) * q8 + (bid >> 3);
    const int bx  = wg % gx;
    const int by  = wg / gx;
    const long row0 = (long)by * 256;
    const int  col0 = bx * 256;

    // per-frag LDS offsets (u16, rel. to A/B region base), kk=0; kk=1 = ^32
    int aoffs[8], boffs[4];
    #pragma unroll
    for (int mf = 0; mf < 8; ++mf) {
        int lr = wm * 128 + mf * 16 + fr;
        aoffs[mf] = lr * 64 + (((lr >> 3) & 1) << 5) + (((g0 ^ (lr >> 1)) & 3) << 3);
    }
    #pragma unroll
    for (int nf = 0; nf < 4; ++nf) {
        int lc = wn * 64 + nf * 16 + fr;
        boffs[nf] = lc * 64 + (((lc >> 3) & 1) << 5) + (((g0 ^ (lc >> 1)) & 3) << 3);
    }

    const int srow = lane >> 3;        // staging: row within 8-row wave slab
    const int scol = (lane & 7) * 8;   // u16 offset within 128B row window

    // precompute A staging physical row bases (4 rows per thread)
    long arow_phys[4];
    #pragma unroll
    for (int half = 0; half < 2; ++half)
        #pragma unroll
        for (int i = 0; i < 2; ++i) {
            int r = half * 128 + i * 64 + wid * 8 + srow;
            long grow = row0 + r;
            arow_phys[half * 2 + i] = A_PERM ? permute_row(grow) : grow;
        }

    // stage one half-tile (128 rows x 64 k): 2 gload16 per thread
    auto stageA = [&](int tt, int half) {
        const int ab = (tt & 1) * 32768;
        #pragma unroll
        for (int i = 0; i < 2; ++i) {
            int r = half * 128 + i * 64 + wid * 8 + srow;
            const u16* g = Ap + arow_phys[half * 2 + i] * 512 + tt * 64 + scol;
            gload16(g, (void*)&lds[ab + r * 64]);
        }
    };
    auto stageB = [&](int tt, int half) {
        const int ab = (tt & 1) * 32768;
        #pragma unroll
        for (int i = 0; i < 2; ++i) {
            int r = half * 128 + i * 64 + wid * 8 + srow;
            const u16* g = Bp + (size_t)(col0 + r) * 512 + tt * 64 + scol;
            gload16(g, (void*)&lds[ab + 16384 + r * 64]);
        }
    };

    f32x4 acc[8][4] = {};

    // ---- prologue: tile0 full + tile1 B (12 loads); keep B(t1) in flight ----
    stageA(0, 0); stageA(0, 1); stageB(0, 0); stageB(0, 1);
    stageB(1, 0); stageB(1, 1);
    asm volatile("s_waitcnt vmcnt(4)" ::: "memory");
    __builtin_amdgcn_sched_barrier(0);
    __builtin_amdgcn_s_barrier();

    #pragma unroll
    for (int t = 0; t < 8; ++t) {
        const int ab = (t & 1) * 32768;
        bf16x8 af0[8], af1[8], bf0[4], bf1[4];
        // ================= phase 0 =================
        #pragma unroll
        for (int mf = 0; mf < 8; ++mf) af0[mf] = LDF(ab + aoffs[mf]);
        #pragma unroll
        for (int nf = 0; nf < 4; ++nf) bf0[nf] = LDF(ab + 16384 + boffs[nf]);
        if (t <= 6) stageA(t + 1, 0);
        __builtin_amdgcn_s_barrier();
        asm volatile("s_waitcnt lgkmcnt(0)" ::: "memory");
        __builtin_amdgcn_sched_barrier(0);
        __builtin_amdgcn_s_setprio(1);
        #pragma unroll
        for (int mf = 0; mf < 8; ++mf) {
            MFMA16(acc[mf][0], af0[mf], bf0[0]);
            MFMA16(acc[mf][1], af0[mf], bf0[1]);
        }
        __builtin_amdgcn_s_setprio(0);
        __builtin_amdgcn_s_barrier();
        // ================= phase 1 =================
        #pragma unroll
        for (int nf = 0; nf < 4; ++nf) bf1[nf] = LDF(ab + 16384 + (boffs[nf] ^ 32));
        if (t <= 6) stageA(t + 1, 1);
        __builtin_amdgcn_s_barrier();
        asm volatile("s_waitcnt lgkmcnt(0)" ::: "memory");
        __builtin_amdgcn_sched_barrier(0);
        __builtin_amdgcn_s_setprio(1);
        #pragma unroll
        for (int mf = 0; mf < 8; ++mf) {
            MFMA16(acc[mf][2], af0[mf], bf0[2]);
            MFMA16(acc[mf][3], af0[mf], bf0[3]);
        }
        __builtin_amdgcn_s_setprio(0);
        __builtin_amdgcn_s_barrier();
        // ================= phase 2 =================
        #pragma unroll
        for (int mf = 0; mf < 8; ++mf) af1[mf] = LDF(ab + (aoffs[mf] ^ 32));
        if (t <= 5) stageB(t + 2, 0);
        __builtin_amdgcn_s_barrier();
        asm volatile("s_waitcnt lgkmcnt(0)" ::: "memory");
        __builtin_amdgcn_sched_barrier(0);
        __builtin_amdgcn_s_setprio(1);
        #pragma unroll
        for (int mf = 0; mf < 8; ++mf) {
            MFMA16(acc[mf][0], af1[mf], bf1[0]);
            MFMA16(acc[mf][1], af1[mf], bf1[1]);
        }
        __builtin_amdgcn_s_setprio(0);
        __builtin_amdgcn_s_barrier();
        // ================= phase 3 =================
        if (t <= 5) stageB(t + 2, 1);
        __builtin_amdgcn_s_barrier();
        __builtin_amdgcn_s_setprio(1);
        #pragma unroll
        for (int mf = 0; mf < 8; ++mf) {
            MFMA16(acc[mf][2], af1[mf], bf1[2]);
            MFMA16(acc[mf][3], af1[mf], bf1[3]);
        }
        __builtin_amdgcn_s_setprio(0);
        if (t <= 5) {
            asm volatile("s_waitcnt vmcnt(4)" ::: "memory");   // t+1 landed, B(t+2) in flight
        } else if (t == 6) {
            asm volatile("s_waitcnt vmcnt(0)" ::: "memory");   // drain before last tile
        }
        __builtin_amdgcn_sched_barrier(0);
        __builtin_amdgcn_s_barrier();
    }

    // ---- epilogue: C row = (lane>>4)*4 + r, col = lane&15 (logical rows) ----
    #pragma unroll
    for (int mf = 0; mf < 8; ++mf) {
        #pragma unroll
        for (int nf = 0; nf < 4; ++nf) {
            #pragma unroll
            for (int r = 0; r < 4; ++r) {
                long grow = row0 + wm * 128 + mf * 16 + (lane >> 4) * 4 + r;
                int  gcol = col0 + wn * 64 + nf * 16 + fr;
                float v = acc[mf][nf][r];
                if constexpr (OUT_BF16) ((u16*)Dp)[grow * NCOL + gcol] = f2bf(v);
                else                    ((float*)Dp)[grow * NCOL + gcol] = v;
            }
        }
    }
}

// ---------------------------------------------------------------------------
// Banded temporal attention. One wave per (b, h, s); grid h-fastest so the 8
// heads of one (b,s) run together on the same 192 KB qkv region.
// qkv rows are (b,s,t)-ordered: row rid=(b*1024+s)*64+t, 1536 elems each ->
// all reads for one (b,s) land in a contiguous 192 KB block.
// Output row rid stored at attn[rid*512] PRE-SWIZZLED with s-based keys
// (s == gemm3's tile-local row mod 256, so gemm3's frag reads line up).
// ---------------------------------------------------------------------------
__global__ __launch_bounds__(64) void attn_k(const u16* __restrict__ qkv,
                                             u16* __restrict__ attn) {
    __shared__ u16 Kl[64][72];
    __shared__ u16 Vl[64][72];

    const int tid = threadIdx.x;
    const int bid = blockIdx.x;
    const int h = bid & (H_ - 1);
    const int s = (bid >> 3) & (S_ - 1);
    const int b = bid >> 13;

    // base of (b,s)'s 64-row slab, offset to head h
    const size_t base = ((size_t)((b << 10) | s) * 64) * 1536 + h * 64;

    {
        const int rr = tid >> 3;
        const int ch = tid & 7;
        #pragma unroll
        for (int it = 0; it < 8; ++it) {
            int tt = it * 8 + rr;
            size_t off = base + (size_t)tt * 1536 + ch * 8;
            *(u16x8*)&Kl[tt][ch * 8] = *(const u16x8*)(qkv + off + 512);
            *(u16x8*)&Vl[tt][ch * 8] = *(const u16x8*)(qkv + off + 1024);
        }
    }
    float qf[64];
    const int t = tid;
    {
        size_t qoff = base + (size_t)t * 1536;
        #pragma unroll
        for (int c = 0; c < 8; ++c) {
            u16x8 v = *(const u16x8*)(qkv + qoff + c * 8);
            #pragma unroll
            for (int j = 0; j < 8; ++j) qf[c * 8 + j] = bf2f(v[j]);
        }
    }
    __syncthreads();

    float p[11];
    float m = -1e30f;
    #pragma unroll
    for (int i = 0; i < 11; ++i) {
        int u = t - WIN_ + i;
        if (u >= 0 && u < 64) {
            float dot = 0.f;
            #pragma unroll
            for (int c = 0; c < 8; ++c) {
                u16x8 kv = *(const u16x8*)&Kl[u][c * 8];
                #pragma unroll
                for (int j = 0; j < 8; ++j) dot += qf[c * 8 + j] * bf2f(kv[j]);
            }
            p[i] = dot * 0.125f;
            m = fmaxf(m, p[i]);
        } else {
            p[i] = -1e30f;
        }
    }
    float sum = 0.f;
    #pragma unroll
    for (int i = 0; i < 11; ++i) {
        int u = t - WIN_ + i;
        float e = (u >= 0 && u < 64) ? __expf(p[i] - m) : 0.f;
        p[i] = e;
        sum += e;
    }
    const float inv = 1.f / sum;

    float o[64];
    #pragma unroll
    for (int d = 0; d < 64; ++d) o[d] = 0.f;
    #pragma unroll
    for (int i = 0; i < 11; ++i) {
        int u = t - WIN_ + i;
        if (u >= 0 && u < 64) {
            float pv = p[i] * inv;
            #pragma unroll
            for (int c = 0; c < 8; ++c) {
                u16x8 vv = *(const u16x8*)&Vl[u][c * 8];
                #pragma unroll
                for (int j = 0; j < 8; ++j) o[c * 8 + j] += pv * bf2f(vv[j]);
            }
        }
    }
    // pre-swizzled store at physical row rid; keys from s (gemm3-local row)
    size_t rowbase = ((size_t)((b << 10) | s) * 64 + t) * (size_t)C_;
    const int cb  = (s >> 3) & 1;
    const int key = (s >> 1) & 3;
    #pragma unroll
    for (int c = 0; c < 8; ++c) {
        u16x8 w;
        #pragma unroll
        for (int j = 0; j < 8; ++j) w[j] = f2bf(o[c * 8 + j]);
        int off = (((2 * h + (c >> 2)) ^ cb) << 5) + (((c & 3) ^ key) << 3);
        *(u16x8*)&attn[rowbase + off] = w;
    }
}

// ---------------------------------------------------------------------------
extern "C" void kernel_launch(void* const* d_in, const int* in_sizes, int n_in,
                              void* d_out, int out_size, void* d_ws, size_t ws_size,
                              hipStream_t stream) {
    const float* x    = (const float*)d_in[0];   // (B, N, C) fp32
    const float* Wqkv = (const float*)d_in[1];   // (512, 1536) fp32
    const float* Wout = (const float*)d_in[2];   // (512, 512) fp32
    float* out = (float*)d_out;

    const size_t xc_elems  = (size_t)M_ * C_;      // 67.1M (x_bf16 / attn alias)
    const size_t qkv_elems = (size_t)M_ * 1536;    // 201.3M
    if (ws_size < (xc_elems + qkv_elems) * sizeof(u16)) return;  // 537 MiB

    u16* xb       = (u16*)d_ws;              // [0, 134MB): x_bf16 (b,s,t)-rows
    u16* qkv      = xb + xc_elems;           // [134MB, 537MB), (b,s,t)-rows
    u16* attn_buf = xb;                      // alias: written after xb is dead
    u16* WqkvT    = (u16*)d_out;             // scratch in d_out (dead until gemm3)
    u16* WoutT    = qkv;                     // alias: written after qkv is dead

    // 1) weight + activation prep (bf16, pre-swizzled; x rows permuted)
    prep_w<<<(1536 * 64) / 256, 256, 0, stream>>>(Wqkv, WqkvT, 1536);
    prep_x<<<8192, 256, 0, stream>>>(x, xb);

    // 2) qkv = x @ W_qkv  (256^2 8-phase, bf16 out, rows already permuted)
    gemm8_k<1536, true, false><<<3072, 512, 0, stream>>>(xb, WqkvT, (void*)qkv, 6);

    // 3) banded temporal attention (contiguous per-(b,s) reads, h-fastest grid)
    attn_k<<<B_ * H_ * S_, 64, 0, stream>>>(qkv, attn_buf);

    // 4) WoutT into the now-dead qkv region
    prep_w<<<(512 * 64) / 256, 256, 0, stream>>>(Wout, WoutT, 512);

    // 5) out = attn @ W_out  (256^2 8-phase, fp32 out coalesced; A un-permuted
    //    via per-lane gload addresses, attn_buf is L3-resident)
    gemm8_k<512, false, true><<<1024, 512, 0, stream>>>(attn_buf, WoutT, (void*)out, 2);
}